// Round 15
// baseline (253.570 us; speedup 1.0000x reference)
//
#include <hip/hip_runtime.h>
#include <stdint.h>

typedef __attribute__((ext_vector_type(8))) short short8;
typedef __attribute__((ext_vector_type(8))) __bf16 bf16x8;
typedef __attribute__((ext_vector_type(4))) float f32x4;
typedef __attribute__((ext_vector_type(2))) float f32x2;

__device__ inline unsigned short f2bf(float f) {
  unsigned u = __float_as_uint(f);
  unsigned r = (u + 0x7FFFu + ((u >> 16) & 1u)) >> 16;  // RNE
  return (unsigned short)r;
}
__device__ inline float bflo(unsigned v) { return __uint_as_float(v << 16); }
__device__ inline float bfhi(unsigned v) { return __uint_as_float(v & 0xFFFF0000u); }
__device__ inline bf16x8 as_bf(short8 v) { return __builtin_bit_cast(bf16x8, v); }
__device__ inline f32x2 up2(unsigned u) { f32x2 r; r.x = bflo(u); r.y = bfhi(u); return r; }
__device__ inline int lbound(const int* a, int n, int v) {
  int lo = 0, hi = n;
  while (lo < hi) { int m = (lo + hi) >> 1; if (a[m] < v) lo = m + 1; else hi = m; }
  return lo;
}

#define GLOAD_LDS16(gp, lp)                                                   \
  __builtin_amdgcn_global_load_lds(                                           \
      (const __attribute__((address_space(1))) void*)(gp),                    \
      (__attribute__((address_space(3))) void*)(lp), 16, 0, 0)

#define NG 1024          // edge-balanced wave ranges (R12-proven)
#define NSL 8            // dim slices (128 dims = 2.5MB, XCD-L2-resident)
#define AGG_BLKS ((NG / 4) * NSL)   // 2048 blocks per branch
#define BM 128
#define BN 128
#define BK 64

// ---------------- prep1: convert_x | wtrans | deg (R12-proven) ----------------
__global__ void prep1_kernel(const float* __restrict__ x0, const float* __restrict__ x1,
                             unsigned short* __restrict__ xb0, unsigned short* __restrict__ xb1,
                             const float* __restrict__ W0, const float* __restrict__ W1,
                             unsigned short* __restrict__ Wt0, unsigned short* __restrict__ Wt1,
                             const int* __restrict__ ei0, const int* __restrict__ ei1,
                             int* __restrict__ dg0, int* __restrict__ dg1,
                             int n, int mpad, int E, int CB) {
  __shared__ float tile[32][33];
  int br = blockIdx.y;
  int b = blockIdx.x;
  int t = threadIdx.x;
  if (b < CB) {
    const float* x = br ? x1 : x0;
    unsigned short* xb = br ? xb1 : xb0;
    long i = (long)b * 256 + t;
    long total = (long)mpad * 128;
    if (i >= total) return;
    long e0 = i * 8;
    int row = (int)(e0 >> 10);
    short8 v;
    if (row < n) {
      const float* s = x + e0;
      float4 fa = *(const float4*)(s);
      float4 fb = *(const float4*)(s + 4);
      v[0] = (short)f2bf(fa.x); v[1] = (short)f2bf(fa.y);
      v[2] = (short)f2bf(fa.z); v[3] = (short)f2bf(fa.w);
      v[4] = (short)f2bf(fb.x); v[5] = (short)f2bf(fb.y);
      v[6] = (short)f2bf(fb.z); v[7] = (short)f2bf(fb.w);
    } else {
      v = (short8)0;
    }
    *(short8*)(xb + e0) = v;
  } else if (b < CB + 1024) {
    const float* W = br ? W1 : W0;
    unsigned short* Wt = br ? Wt1 : Wt0;
    int bb = b - CB;
    int bx = bb & 31;
    int by = bb >> 5;
    int tx = t & 31, ty = t >> 5;
#pragma unroll
    for (int r = 0; r < 4; ++r) {
      int k = by * 32 + ty + r * 8;
      tile[ty + r * 8][tx] = W[(long)k * 1024 + bx * 32 + tx];
    }
    __syncthreads();
#pragma unroll
    for (int r = 0; r < 4; ++r) {
      int nrow = bx * 32 + ty + r * 8;
      int kcol = by * 32 + tx;
      Wt[(long)nrow * 1024 + kcol] = f2bf(tile[tx][ty + r * 8]);
    }
  } else {
    const int* ei = br ? ei1 : ei0;
    int* degi = br ? dg1 : dg0;
    int e = (b - CB - 1024) * 256 + t;
    if (e >= E) return;
    atomicAdd(&degi[ei[E + e]], 1);
  }
}

// scan over padded (deg+1 -> mult of 4); self-loop folded as edge (R12-proven)
__global__ __launch_bounds__(1024) void scan2_kernel(
    const int* __restrict__ degA, int* __restrict__ offA, int* __restrict__ curA,
    const int* __restrict__ degB, int* __restrict__ offB, int* __restrict__ curB, int n) {
  const int* deg = blockIdx.x ? degB : degA;
  int* off = blockIdx.x ? offB : offA;
  int* cur = blockIdx.x ? curB : curA;
  __shared__ int wsum[17];
  int t = threadIdx.x, lane = t & 63, w = t >> 6;
  int CH = (n + 1023) >> 10;
  int i0 = t * CH;
  int s = 0;
  for (int i = 0; i < CH; ++i) {
    int idx = i0 + i;
    s += (idx < n) ? ((deg[idx] + 4) & ~3) : 0;
  }
  int inc = s;
  for (int d = 1; d < 64; d <<= 1) {
    int x = __shfl_up(inc, d);
    if (lane >= d) inc += x;
  }
  if (lane == 63) wsum[w] = inc;
  __syncthreads();
  if (t == 0) {
    int r = 0;
    for (int k = 0; k < 16; ++k) { int x = wsum[k]; wsum[k] = r; r += x; }
    wsum[16] = r;
  }
  __syncthreads();
  int run = wsum[w] + inc - s;
  for (int i = 0; i < CH; ++i) {
    int idx = i0 + i;
    if (idx < n) {
      off[idx] = run;
      cur[idx] = run;
      run += (deg[idx] + 4) & ~3;
    }
  }
  if (t == 0) off[n] = wsum[16];
}

// ---------------- device bodies ----------------
__device__ void fill_body(const int* __restrict__ ei, const int* __restrict__ dg,
                          int* __restrict__ cur, uint2* __restrict__ cw,
                          int b, int t, int E, int N) {
  int e = b * 256 + t;
  if (e >= E + N) return;
  int s, d; float w;
  if (e < E) {
    s = ei[e]; d = ei[E + e];
    w = rsqrtf((float)(dg[s] + 1)) * rsqrtf((float)(dg[d] + 1));
  } else {
    s = e - E; d = s;
    w = 1.0f / (float)(dg[s] + 1);
  }
  int p = atomicAdd(&cur[d], 1);
  uint2 v; v.x = (unsigned)s * 2048u; v.y = __float_as_uint(w);
  cw[p] = v;
}

__device__ void ranges_body(const int* __restrict__ off, int* __restrict__ rng,
                            int b, int t, int N) {
  int q = b * 256 + t;
  if (q > NG) return;
  if (q == NG) { rng[q] = N; return; }
  long Etot = off[N];
  long target = (long)q * Etot;
  int lo = 0, hi = N;
  while (lo < hi) {
    int mid = (lo + hi) >> 1;
    if ((long)off[mid] * NG >= target) hi = mid; else lo = mid + 1;
  }
  rng[q] = lo;
}

// GEMM body (R12-proven: BK=64, XOR chunk swizzle, gload_lds both, XCD-coop mapping)
__device__ __forceinline__ void gemm_body(const unsigned short* __restrict__ A,
                                          const unsigned short* __restrict__ Bt,
                                          unsigned short* __restrict__ C,
                                          int x, int Nn, int K) {
  __shared__ alignas(16) unsigned short As[BM * BK];
  __shared__ alignas(16) unsigned short Bs[BN * BK];
  long m0 = (long)((x >> 6) * 8 + (x & 7)) * BM;
  long n0 = (long)((x >> 3) & 7) * BN;
  int t = threadIdx.x;
  int lane = t & 63;
  int w = t >> 6;
  int wm = (w >> 1) * 64, wn = (w & 1) * 64;
  int l3 = lane >> 3;
  int gsw = (lane & 7) ^ l3;
  int srowb = w * 8 + l3;
  const unsigned short* Ag = A + (m0 + srowb) * K + gsw * 8;
  const unsigned short* Bg = Bt + (n0 + srowb) * K + gsw * 8;
  unsigned short* AsP = As + t * 8;
  unsigned short* BsP = Bs + t * 8;
  int fr = lane & 15;
  int c0 = (lane >> 4) ^ (lane & 7);
  const unsigned short* afp0 = As + (wm + fr) * BK + c0 * 8;
  const unsigned short* afp1 = As + (wm + fr) * BK + (c0 ^ 4) * 8;
  const unsigned short* bfp0 = Bs + (wn + fr) * BK + c0 * 8;
  const unsigned short* bfp1 = Bs + (wn + fr) * BK + (c0 ^ 4) * 8;
  f32x4 acc[4][4] = {};
  for (int k0 = 0; k0 < K; k0 += BK) {
    __syncthreads();
#pragma unroll
    for (int j = 0; j < 4; ++j) {
      GLOAD_LDS16(Ag + (long)(j * 32) * K + k0, AsP + j * 2048);
      GLOAD_LDS16(Bg + (long)(j * 32) * K + k0, BsP + j * 2048);
    }
    __syncthreads();
    short8 af[4][2], bf[4][2];
#pragma unroll
    for (int i = 0; i < 4; ++i) {
      af[i][0] = *(const short8*)(afp0 + i * 16 * BK);
      af[i][1] = *(const short8*)(afp1 + i * 16 * BK);
    }
#pragma unroll
    for (int i = 0; i < 4; ++i) {
      bf[i][0] = *(const short8*)(bfp0 + i * 16 * BK);
      bf[i][1] = *(const short8*)(bfp1 + i * 16 * BK);
    }
#pragma unroll
    for (int i = 0; i < 4; ++i)
#pragma unroll
      for (int j = 0; j < 4; ++j) {
        acc[i][j] = __builtin_amdgcn_mfma_f32_16x16x32_bf16(as_bf(af[i][0]), as_bf(bf[j][0]),
                                                            acc[i][j], 0, 0, 0);
        acc[i][j] = __builtin_amdgcn_mfma_f32_16x16x32_bf16(as_bf(af[i][1]), as_bf(bf[j][1]),
                                                            acc[i][j], 0, 0, 0);
      }
  }
  int cr = (lane >> 4) * 4;
  int cc = lane & 15;
#pragma unroll
  for (int i = 0; i < 4; ++i)
#pragma unroll
    for (int j = 0; j < 4; ++j) {
      long row = m0 + wm + i * 16 + cr;
      long col = n0 + wn + j * 16 + cc;
      unsigned short* cp = C + row * Nn + col;
#pragma unroll
      for (int r = 0; r < 4; ++r)
        cp[(long)r * Nn] = f2bf(acc[i][j][r]);
    }
}

// agg body (R12-proven: wave-owns-node, 4-edge quads, pipelined, pk-fma, shfl reduce)
__device__ void agg_body(const uint8_t* __restrict__ Hb, const int* __restrict__ off,
                         const uint2* __restrict__ cw, const int* __restrict__ batch,
                         const int* __restrict__ rng, const float* __restrict__ bias,
                         float* __restrict__ pool, float* __restrict__ scratch,
                         int* __restrict__ gid, int blk) {
  int t = threadIdx.x;
  int wv = t >> 6, lane = t & 63, qw = lane >> 4, l16 = lane & 15;
  int slice = blk & 7;
  int part = blk >> 3;
  int q = part * 4 + wv;
  int d0 = slice * 128 + l16 * 8;
  unsigned d0b = (unsigned)d0 * 2;
  float4 bv0 = *(const float4*)(bias + d0);
  float4 bv1 = *(const float4*)(bias + d0 + 4);
  int na = rng[q], nb = rng[q + 1];
  int g0 = -1, g1 = -1;
  if (na < nb) {
    float bv[8] = {bv0.x, bv0.y, bv0.z, bv0.w, bv1.x, bv1.y, bv1.z, bv1.w};
    float pacc[8] = {};
    f32x2 a2[4] = {};
    int curg = batch[na];
    int fi = 0;
    int nd = na;
    int ee = off[na + 1];
    int eend = off[nb];
    int e = off[na];
    uint2 cc = cw[e + qw];
    uint2 cn = cw[e + 4 + qw];
    uint4 hc = *(const uint4*)(Hb + (cc.x + d0b));
#pragma unroll 2
    for (; e < eend; e += 4) {
      uint4 hn = *(const uint4*)(Hb + (cn.x + d0b));
      uint2 c2 = cw[e + 8 + qw];
      float w = __uint_as_float(cc.y);
      f32x2 w2; w2.x = w; w2.y = w;
      a2[0] += w2 * up2(hc.x);
      a2[1] += w2 * up2(hc.y);
      a2[2] += w2 * up2(hc.z);
      a2[3] += w2 * up2(hc.w);
      cc = cn; cn = c2; hc = hn;
      if (e + 4 == ee) {   // node nd complete (wave-uniform)
#pragma unroll
        for (int k = 0; k < 8; ++k) {
          float v = (k & 1) ? a2[k >> 1].y : a2[k >> 1].x;
          v += __shfl_xor(v, 16);
          v += __shfl_xor(v, 32);
          v += bv[k];
          pacc[k] += (v >= 0.f) ? v : 0.01f * v;
        }
#pragma unroll
        for (int k = 0; k < 4; ++k) { a2[k].x = 0.f; a2[k].y = 0.f; }
        ++nd;
        if (nd < nb) {
          ee = off[nd + 1];
          int g = batch[nd];
          if (g != curg) {
            if (fi == 0) {
              g0 = curg;
              if (qw == 0) {
                float* sp = scratch + ((long)q * 2 + 0) * 1024 + d0;
                *(float4*)sp = make_float4(pacc[0], pacc[1], pacc[2], pacc[3]);
                *(float4*)(sp + 4) = make_float4(pacc[4], pacc[5], pacc[6], pacc[7]);
              }
            } else {
              if (qw == 0) {
                float* pp = pool + (long)curg * 1024 + d0;
#pragma unroll
                for (int k = 0; k < 8; ++k) atomicAdd(pp + k, pacc[k]);
              }
            }
            ++fi;
#pragma unroll
            for (int k = 0; k < 8; ++k) pacc[k] = 0.f;
            curg = g;
          }
        }
      }
    }
    if (fi == 0) {
      g0 = curg;
      if (qw == 0) {
        float* sp = scratch + ((long)q * 2 + 0) * 1024 + d0;
        *(float4*)sp = make_float4(pacc[0], pacc[1], pacc[2], pacc[3]);
        *(float4*)(sp + 4) = make_float4(pacc[4], pacc[5], pacc[6], pacc[7]);
      }
    } else {
      g1 = curg;
      if (qw == 0) {
        float* sp = scratch + ((long)q * 2 + 1) * 1024 + d0;
        *(float4*)sp = make_float4(pacc[0], pacc[1], pacc[2], pacc[3]);
        *(float4*)(sp + 4) = make_float4(pacc[4], pacc[5], pacc[6], pacc[7]);
      }
    }
  }
  if (slice == 0 && lane == 0) {
    gid[q * 2] = g0;
    gid[q * 2 + 1] = g1;
  }
}

// pool_reduce body (R12-proven) + optional out init
__device__ void pool_reduce_body(const float* __restrict__ scratch, const int* __restrict__ gid,
                                 const int* __restrict__ batch, const int* __restrict__ rng,
                                 const float* __restrict__ pool, float* __restrict__ pm,
                                 int blk, int N,
                                 const float* __restrict__ finb, float* __restrict__ out, int nb_) {
  int g = blk >> 2;
  int slice = blk & 3;
  int tid = threadIdx.x;
  if (out && blk == 0 && tid < nb_) out[tid] = finb[0];
  int gs = lbound(batch, N, g), ge = lbound(batch, N, g + 1);
  float ic = 1.0f / (float)max(ge - gs, 1);
  int qlo = max(lbound(rng, NG + 1, gs + 1) - 1, 0);
  int qhi = min(lbound(rng, NG + 1, ge) - 1, NG - 1);
  long idx = (long)g * 1024 + slice * 256 + tid;
  float s = pool[idx];
  if (gs < ge) {
    for (int q = qlo; q <= qhi; ++q) {
      int a = gid[q * 2], b = gid[q * 2 + 1];
      if (a == g) s += scratch[((long)q * 2 + 0) * 1024 + slice * 256 + tid];
      if (b == g) s += scratch[((long)q * 2 + 1) * 1024 + slice * 256 + tid];
    }
  }
  pm[idx] = s * ic;
}

// fc head body (256-thread variant): FC + leaky + finW partial -> atomicAdd out
__device__ void fc_head_body(const float* __restrict__ pm, const float* __restrict__ W,
                             const float* __restrict__ bb, const float* __restrict__ finW,
                             float* __restrict__ out, int g, int half) {
  __shared__ float p[1024];
  __shared__ float red[256];
  int t = threadIdx.x;
  for (int i = t; i < 1024; i += 256) p[i] = pm[(long)g * 1024 + i];
  __syncthreads();
  int col = t & 127, kh = t >> 7;
  const float* Wp = W + (long)(kh * 512) * 128 + col;
  const float* pk = p + kh * 512;
  float a = 0.f;
#pragma unroll 8
  for (int k = 0; k < 512; ++k) a += pk[k] * Wp[(long)k * 128];
  red[t] = a;
  __syncthreads();
  if (t < 128) {
    float s = red[t] + red[t + 128] + bb[t];
    s = s >= 0.f ? s : 0.01f * s;
    red[t] = s * finW[half * 128 + t];
  }
  __syncthreads();
  for (int st = 64; st; st >>= 1) {
    if (t < st) red[t] += red[t + st];
    __syncthreads();
  }
  if (t == 0) atomicAdd(&out[g], red[0]);
}

// ---------------- mega kernels (role-split for dispatch overlap) ----------------
// mega0: fill br0 | fill br1 | ranges br0 | ranges br1 | gemm br0
__global__ __launch_bounds__(256) void mega0_kernel(
    const int* ei0, const int* ei1, const int* dg0, const int* dg1,
    int* cur0, int* cur1, uint2* cw0, uint2* cw1,
    const int* off0, const int* off1, int* rng0, int* rng1,
    const unsigned short* xb0, const unsigned short* wt0, unsigned short* h0,
    int E, int N, int FB, int RB) {
  int b = blockIdx.x;
  if (b < FB) fill_body(ei0, dg0, cur0, cw0, b, threadIdx.x, E, N);
  else if (b < 2 * FB) fill_body(ei1, dg1, cur1, cw1, b - FB, threadIdx.x, E, N);
  else if (b < 2 * FB + RB) ranges_body(off0, rng0, b - 2 * FB, threadIdx.x, N);
  else if (b < 2 * FB + 2 * RB) ranges_body(off1, rng1, b - 2 * FB - RB, threadIdx.x, N);
  else gemm_body(xb0, wt0, h0, b - 2 * FB - 2 * RB, 1024, 1024);
}

// mega1: agg br0 | gemm br1
__global__ __launch_bounds__(256) void mega1_kernel(
    const unsigned short* h0, const int* off0, const uint2* cw0, const int* b0,
    const int* rng0, const float* bias0, float* pool0, float* scr0, int* gid0,
    const unsigned short* xb1, const unsigned short* wt1, unsigned short* h1) {
  int b = blockIdx.x;
  if (b < AGG_BLKS)
    agg_body((const uint8_t*)h0, off0, cw0, b0, rng0, bias0, pool0, scr0, gid0, b);
  else
    gemm_body(xb1, wt1, h1, b - AGG_BLKS, 1024, 1024);
}

// mega2: agg br1 | pool_reduce br0 (+out init)
__global__ __launch_bounds__(256) void mega2_kernel(
    const unsigned short* h1, const int* off1, const uint2* cw1, const int* b1,
    const int* rng1, const float* bias1, float* pool1, float* scr1, int* gid1,
    const float* scr0, const int* gid0, const int* b0, const int* rng0,
    const float* pool0, float* pm0, const float* finb, float* out, int N, int nb_) {
  int b = blockIdx.x;
  if (b < AGG_BLKS)
    agg_body((const uint8_t*)h1, off1, cw1, b1, rng1, bias1, pool1, scr1, gid1, b);
  else
    pool_reduce_body(scr0, gid0, b0, rng0, pool0, pm0, b - AGG_BLKS, N, finb, out, nb_);
}

// mega3: pool_reduce br1 | fc_head br0
__global__ __launch_bounds__(256) void mega3_kernel(
    const float* scr1, const int* gid1, const int* b1, const int* rng1,
    const float* pool1, float* pm1, int N, int PRB,
    const float* pm0, const float* fc1W, const float* fc1b, const float* finW, float* out) {
  int b = blockIdx.x;
  if (b < PRB)
    pool_reduce_body(scr1, gid1, b1, rng1, pool1, pm1, b, N, nullptr, nullptr, 0);
  else
    fc_head_body(pm0, fc1W, fc1b, finW, out, b - PRB, 0);
}

// tail: fc_head br1
__global__ __launch_bounds__(256) void fc_tail_kernel(
    const float* pm1, const float* fc2W, const float* fc2b, const float* finW, float* out) {
  fc_head_body(pm1, fc2W, fc2b, finW, out, blockIdx.x, 1);
}

extern "C" void kernel_launch(void* const* d_in, const int* in_sizes, int n_in,
                              void* d_out, int out_size, void* d_ws, size_t ws_size,
                              hipStream_t stream) {
  (void)n_in; (void)ws_size;
  const float* xs[2]   = {(const float*)d_in[0], (const float*)d_in[3]};
  const int* eis[2]    = {(const int*)d_in[1], (const int*)d_in[4]};
  const int* bts[2]    = {(const int*)d_in[2], (const int*)d_in[5]};
  const float* Ws[2]   = {(const float*)d_in[6], (const float*)d_in[10]};
  const float* bs[2]   = {(const float*)d_in[7], (const float*)d_in[11]};
  const float* fc1W = (const float*)d_in[8];
  const float* fc1b = (const float*)d_in[9];
  const float* fc2W = (const float*)d_in[12];
  const float* fc2b = (const float*)d_in[13];
  const float* finW = (const float*)d_in[14];
  const float* finb = (const float*)d_in[15];
  float* out = (float*)d_out;

  const int N = in_sizes[2];
  const int E = in_sizes[1] / 2;
  const int Mpad = ((N + 1023) / 1024) * 1024;   // MT multiple of 8 for XCD mapping
  const int MT = Mpad / BM;
  const int CWCAP = E + 4 * N + 64;              // padded CSR capacity

  uint8_t* ws = (uint8_t*)d_ws;
  size_t o = 0;
  auto alloc = [&](size_t bytes) { size_t r = o; o += (bytes + 255) & ~(size_t)255; return r; };
  size_t degi_o[2] = {alloc((size_t)N * 4), alloc((size_t)N * 4)};
  size_t pool_o[2] = {alloc((size_t)out_size * 1024 * 4), alloc((size_t)out_size * 1024 * 4)};
  size_t cw_o[2]   = {alloc((size_t)CWCAP * 8), alloc((size_t)CWCAP * 8)};
  size_t zero_end = o;
  size_t cur_o[2]  = {alloc((size_t)N * 4), alloc((size_t)N * 4)};
  size_t off_o[2]  = {alloc((size_t)(N + 1) * 4), alloc((size_t)(N + 1) * 4)};
  size_t rng_o[2]  = {alloc((size_t)(NG + 1) * 4), alloc((size_t)(NG + 1) * 4)};
  size_t gid_o[2]  = {alloc((size_t)NG * 2 * 4), alloc((size_t)NG * 2 * 4)};
  size_t scr_o[2]  = {alloc((size_t)NG * 2 * 1024 * 4), alloc((size_t)NG * 2 * 1024 * 4)};
  size_t pm_o[2]   = {alloc((size_t)out_size * 1024 * 4), alloc((size_t)out_size * 1024 * 4)};
  size_t xb_o[2]   = {alloc((size_t)Mpad * 1024 * 2), alloc((size_t)Mpad * 1024 * 2)};
  size_t wt_o[2]   = {alloc((size_t)1024 * 1024 * 2), alloc((size_t)1024 * 1024 * 2)};
  size_t h_o[2]    = {alloc((size_t)Mpad * 1024 * 2), alloc((size_t)Mpad * 1024 * 2)};

  (void)hipMemsetAsync(ws, 0, zero_end, stream);

  const int CB = (int)(((long)Mpad * 128 + 255) / 256);
  const int DB = (E + 255) / 256;
  prep1_kernel<<<dim3(CB + 1024 + DB, 2), 256, 0, stream>>>(
      xs[0], xs[1], (unsigned short*)(ws + xb_o[0]), (unsigned short*)(ws + xb_o[1]),
      Ws[0], Ws[1], (unsigned short*)(ws + wt_o[0]), (unsigned short*)(ws + wt_o[1]),
      eis[0], eis[1], (int*)(ws + degi_o[0]), (int*)(ws + degi_o[1]),
      N, Mpad, E, CB);
  scan2_kernel<<<2, 1024, 0, stream>>>(
      (const int*)(ws + degi_o[0]), (int*)(ws + off_o[0]), (int*)(ws + cur_o[0]),
      (const int*)(ws + degi_o[1]), (int*)(ws + off_o[1]), (int*)(ws + cur_o[1]), N);
  const int FB = (E + N + 255) / 256;
  const int RB = (NG + 256) / 256;
  mega0_kernel<<<2 * FB + 2 * RB + MT * 8, 256, 0, stream>>>(
      eis[0], eis[1], (const int*)(ws + degi_o[0]), (const int*)(ws + degi_o[1]),
      (int*)(ws + cur_o[0]), (int*)(ws + cur_o[1]),
      (uint2*)(ws + cw_o[0]), (uint2*)(ws + cw_o[1]),
      (const int*)(ws + off_o[0]), (const int*)(ws + off_o[1]),
      (int*)(ws + rng_o[0]), (int*)(ws + rng_o[1]),
      (const unsigned short*)(ws + xb_o[0]), (const unsigned short*)(ws + wt_o[0]),
      (unsigned short*)(ws + h_o[0]), E, N, FB, RB);
  mega1_kernel<<<AGG_BLKS + MT * 8, 256, 0, stream>>>(
      (const unsigned short*)(ws + h_o[0]), (const int*)(ws + off_o[0]),
      (const uint2*)(ws + cw_o[0]), bts[0], (const int*)(ws + rng_o[0]), bs[0],
      (float*)(ws + pool_o[0]), (float*)(ws + scr_o[0]), (int*)(ws + gid_o[0]),
      (const unsigned short*)(ws + xb_o[1]), (const unsigned short*)(ws + wt_o[1]),
      (unsigned short*)(ws + h_o[1]));
  mega2_kernel<<<AGG_BLKS + out_size * 4, 256, 0, stream>>>(
      (const unsigned short*)(ws + h_o[1]), (const int*)(ws + off_o[1]),
      (const uint2*)(ws + cw_o[1]), bts[1], (const int*)(ws + rng_o[1]), bs[1],
      (float*)(ws + pool_o[1]), (float*)(ws + scr_o[1]), (int*)(ws + gid_o[1]),
      (const float*)(ws + scr_o[0]), (const int*)(ws + gid_o[0]), bts[0],
      (const int*)(ws + rng_o[0]), (const float*)(ws + pool_o[0]),
      (float*)(ws + pm_o[0]), finb, out, N, out_size);
  mega3_kernel<<<out_size * 4 + out_size, 256, 0, stream>>>(
      (const float*)(ws + scr_o[1]), (const int*)(ws + gid_o[1]), bts[1],
      (const int*)(ws + rng_o[1]), (const float*)(ws + pool_o[1]),
      (float*)(ws + pm_o[1]), N, out_size * 4,
      (const float*)(ws + pm_o[0]), fc1W, fc1b, finW, out);
  fc_tail_kernel<<<out_size, 256, 0, stream>>>(
      (const float*)(ws + pm_o[1]), fc2W, fc2b, finW, out);
}

// Round 16
// 208.873 us; speedup vs baseline: 1.2140x; 1.2140x over previous
//
#include <hip/hip_runtime.h>
#include <stdint.h>

typedef __attribute__((ext_vector_type(8))) short short8;
typedef __attribute__((ext_vector_type(8))) __bf16 bf16x8;
typedef __attribute__((ext_vector_type(4))) float f32x4;
typedef __attribute__((ext_vector_type(2))) float f32x2;

__device__ inline unsigned short f2bf(float f) {
  unsigned u = __float_as_uint(f);
  unsigned r = (u + 0x7FFFu + ((u >> 16) & 1u)) >> 16;  // RNE
  return (unsigned short)r;
}
__device__ inline float bflo(unsigned v) { return __uint_as_float(v << 16); }
__device__ inline float bfhi(unsigned v) { return __uint_as_float(v & 0xFFFF0000u); }
__device__ inline bf16x8 as_bf(short8 v) { return __builtin_bit_cast(bf16x8, v); }
__device__ inline f32x2 up2(unsigned u) { f32x2 r; r.x = bflo(u); r.y = bfhi(u); return r; }
// first i in [0,n) with a[i] >= v  (a ascending)
__device__ inline int lbound(const int* a, int n, int v) {
  int lo = 0, hi = n;
  while (lo < hi) { int m = (lo + hi) >> 1; if (a[m] < v) lo = m + 1; else hi = m; }
  return lo;
}

#define GLOAD_LDS16(gp, lp)                                                   \
  __builtin_amdgcn_global_load_lds(                                           \
      (const __attribute__((address_space(1))) void*)(gp),                    \
      (__attribute__((address_space(3))) void*)(lp), 16, 0, 0)

#define NG 1024   // edge-balanced node ranges
#define NSL 8     // dim slices (128 dims = 2.5MB, XCD-L2-resident)

// ---------------- fused prep1: convert_x | wtrans | deg ----------------
__global__ void prep1_kernel(const float* __restrict__ x0, const float* __restrict__ x1,
                             unsigned short* __restrict__ xb0, unsigned short* __restrict__ xb1,
                             const float* __restrict__ W0, const float* __restrict__ W1,
                             unsigned short* __restrict__ Wt0, unsigned short* __restrict__ Wt1,
                             const int* __restrict__ ei0, const int* __restrict__ ei1,
                             int* __restrict__ dg0, int* __restrict__ dg1,
                             int n, int mpad, int E, int CB) {
  __shared__ float tile[32][33];
  int br = blockIdx.y;
  int b = blockIdx.x;
  int t = threadIdx.x;
  if (b < CB) {
    const float* x = br ? x1 : x0;
    unsigned short* xb = br ? xb1 : xb0;
    long i = (long)b * 256 + t;
    long total = (long)mpad * 128;
    if (i >= total) return;
    long e0 = i * 8;
    int row = (int)(e0 >> 10);
    short8 v;
    if (row < n) {
      const float* s = x + e0;
      float4 fa = *(const float4*)(s);
      float4 fb = *(const float4*)(s + 4);
      v[0] = (short)f2bf(fa.x); v[1] = (short)f2bf(fa.y);
      v[2] = (short)f2bf(fa.z); v[3] = (short)f2bf(fa.w);
      v[4] = (short)f2bf(fb.x); v[5] = (short)f2bf(fb.y);
      v[6] = (short)f2bf(fb.z); v[7] = (short)f2bf(fb.w);
    } else {
      v = (short8)0;
    }
    *(short8*)(xb + e0) = v;
  } else if (b < CB + 1024) {
    const float* W = br ? W1 : W0;
    unsigned short* Wt = br ? Wt1 : Wt0;
    int bb = b - CB;
    int bx = bb & 31;
    int by = bb >> 5;
    int tx = t & 31, ty = t >> 5;
#pragma unroll
    for (int r = 0; r < 4; ++r) {
      int k = by * 32 + ty + r * 8;
      tile[ty + r * 8][tx] = W[(long)k * 1024 + bx * 32 + tx];
    }
    __syncthreads();
#pragma unroll
    for (int r = 0; r < 4; ++r) {
      int nrow = bx * 32 + ty + r * 8;
      int kcol = by * 32 + tx;
      Wt[(long)nrow * 1024 + kcol] = f2bf(tile[tx][ty + r * 8]);
    }
  } else {
    const int* ei = br ? ei1 : ei0;
    int* degi = br ? dg1 : dg0;
    int e = (b - CB - 1024) * 256 + t;
    if (e >= E) return;
    atomicAdd(&degi[ei[E + e]], 1);
  }
}

// one-pass scan over padded (deg+1 -> mult of 4); self-loop folded as edge
__global__ __launch_bounds__(1024) void scan2_kernel(
    const int* __restrict__ degA, int* __restrict__ offA, int* __restrict__ curA,
    const int* __restrict__ degB, int* __restrict__ offB, int* __restrict__ curB, int n) {
  const int* deg = blockIdx.x ? degB : degA;
  int* off = blockIdx.x ? offB : offA;
  int* cur = blockIdx.x ? curB : curA;
  __shared__ int wsum[17];
  int t = threadIdx.x, lane = t & 63, w = t >> 6;
  int CH = (n + 1023) >> 10;
  int i0 = t * CH;
  int s = 0;
  for (int i = 0; i < CH; ++i) {
    int idx = i0 + i;
    s += (idx < n) ? ((deg[idx] + 4) & ~3) : 0;
  }
  int inc = s;
  for (int d = 1; d < 64; d <<= 1) {
    int x = __shfl_up(inc, d);
    if (lane >= d) inc += x;
  }
  if (lane == 63) wsum[w] = inc;
  __syncthreads();
  if (t == 0) {
    int r = 0;
    for (int k = 0; k < 16; ++k) { int x = wsum[k]; wsum[k] = r; r += x; }
    wsum[16] = r;
  }
  __syncthreads();
  int run = wsum[w] + inc - s;
  for (int i = 0; i < CH; ++i) {
    int idx = i0 + i;
    if (idx < n) {
      off[idx] = run;
      cur[idx] = run;
      run += (deg[idx] + 4) & ~3;
    }
  }
  if (t == 0) off[n] = wsum[16];
}

// ---------------- fused prep2: fill | ranges ----------------
__global__ void prep2_kernel(const int* __restrict__ ei0, const int* __restrict__ ei1,
                             const int* __restrict__ dg0, const int* __restrict__ dg1,
                             int* __restrict__ cur0, int* __restrict__ cur1,
                             uint2* __restrict__ cw0, uint2* __restrict__ cw1,
                             const int* __restrict__ off0, const int* __restrict__ off1,
                             int* __restrict__ rng0, int* __restrict__ rng1,
                             int E, int N, int FB) {
  int br = blockIdx.y;
  int b = blockIdx.x;
  int t = threadIdx.x;
  if (b < FB) {
    const int* ei = br ? ei1 : ei0;
    const int* dg = br ? dg1 : dg0;
    int* cur = br ? cur1 : cur0;
    uint2* cw = br ? cw1 : cw0;
    int e = b * 256 + t;
    if (e >= E + N) return;
    int s, d; float w;
    if (e < E) {
      s = ei[e]; d = ei[E + e];
      w = rsqrtf((float)(dg[s] + 1)) * rsqrtf((float)(dg[d] + 1));
    } else {
      s = e - E; d = s;
      w = 1.0f / (float)(dg[s] + 1);
    }
    int p = atomicAdd(&cur[d], 1);
    uint2 v; v.x = (unsigned)s * 2048u; v.y = __float_as_uint(w);
    cw[p] = v;
  } else {
    const int* off = br ? off1 : off0;
    int* rng = br ? rng1 : rng0;
    int q = (b - FB) * 256 + t;
    if (q > NG) return;
    if (q == NG) { rng[q] = N; return; }
    long Etot = off[N];
    long target = (long)q * Etot;
    int lo = 0, hi = N;
    while (lo < hi) {
      int mid = (lo + hi) >> 1;
      if ((long)off[mid] * NG >= target) hi = mid; else lo = mid + 1;
    }
    rng[q] = lo;
  }
}

// ---------------- GEMM: C[M,N] = A[M,K] @ Bt[N,K]^T (R9 version, proven) ----------------
#define BM 128
#define BN 128
#define BK 64

__global__ __launch_bounds__(256) void gemm_bf16_kernel(
    const unsigned short* __restrict__ A0, const unsigned short* __restrict__ A1,
    const unsigned short* __restrict__ B0, const unsigned short* __restrict__ B1,
    unsigned short* __restrict__ C0, unsigned short* __restrict__ C1,
    int Nn, int K) {
  const unsigned short* A = blockIdx.z ? A1 : A0;
  const unsigned short* Bt = blockIdx.z ? B1 : B0;
  unsigned short* C = blockIdx.z ? C1 : C0;
  __shared__ alignas(16) unsigned short As[BM * BK];
  __shared__ alignas(16) unsigned short Bs[BN * BK];
  int x = blockIdx.x;
  long m0 = (long)((x >> 6) * 8 + (x & 7)) * BM;
  long n0 = (long)((x >> 3) & 7) * BN;
  int t = threadIdx.x;
  int lane = t & 63;
  int w = t >> 6;
  int wm = (w >> 1) * 64, wn = (w & 1) * 64;
  int l3 = lane >> 3;
  int gsw = (lane & 7) ^ l3;
  int srowb = w * 8 + l3;
  const unsigned short* Ag = A + (m0 + srowb) * K + gsw * 8;
  const unsigned short* Bg = Bt + (n0 + srowb) * K + gsw * 8;
  unsigned short* AsP = As + t * 8;
  unsigned short* BsP = Bs + t * 8;
  int fr = lane & 15;
  int c0 = (lane >> 4) ^ (lane & 7);
  const unsigned short* afp0 = As + (wm + fr) * BK + c0 * 8;
  const unsigned short* afp1 = As + (wm + fr) * BK + (c0 ^ 4) * 8;
  const unsigned short* bfp0 = Bs + (wn + fr) * BK + c0 * 8;
  const unsigned short* bfp1 = Bs + (wn + fr) * BK + (c0 ^ 4) * 8;
  f32x4 acc[4][4] = {};
  for (int k0 = 0; k0 < K; k0 += BK) {
    __syncthreads();
#pragma unroll
    for (int j = 0; j < 4; ++j) {
      GLOAD_LDS16(Ag + (long)(j * 32) * K + k0, AsP + j * 2048);
      GLOAD_LDS16(Bg + (long)(j * 32) * K + k0, BsP + j * 2048);
    }
    __syncthreads();
    short8 af[4][2], bf[4][2];
#pragma unroll
    for (int i = 0; i < 4; ++i) {
      af[i][0] = *(const short8*)(afp0 + i * 16 * BK);
      af[i][1] = *(const short8*)(afp1 + i * 16 * BK);
    }
#pragma unroll
    for (int i = 0; i < 4; ++i) {
      bf[i][0] = *(const short8*)(bfp0 + i * 16 * BK);
      bf[i][1] = *(const short8*)(bfp1 + i * 16 * BK);
    }
#pragma unroll
    for (int i = 0; i < 4; ++i)
#pragma unroll
      for (int j = 0; j < 4; ++j) {
        acc[i][j] = __builtin_amdgcn_mfma_f32_16x16x32_bf16(as_bf(af[i][0]), as_bf(bf[j][0]),
                                                            acc[i][j], 0, 0, 0);
        acc[i][j] = __builtin_amdgcn_mfma_f32_16x16x32_bf16(as_bf(af[i][1]), as_bf(bf[j][1]),
                                                            acc[i][j], 0, 0, 0);
      }
  }
  int cr = (lane >> 4) * 4;
  int cc = lane & 15;
#pragma unroll
  for (int i = 0; i < 4; ++i)
#pragma unroll
    for (int j = 0; j < 4; ++j) {
      long row = m0 + wm + i * 16 + cr;
      long col = n0 + wn + j * 16 + cc;
      unsigned short* cp = C + row * Nn + col;
#pragma unroll
      for (int r = 0; r < 4; ++r)
        cp[(long)r * Nn] = f2bf(acc[i][j][r]);
    }
}

// ---------------- fused aggregate + bias + leaky + partial-pool (pipelined, pk-fma) ----------------
__global__ __launch_bounds__(256) void agg_pool_kernel(
    const unsigned short* __restrict__ H0, const unsigned short* __restrict__ H1,
    const int* __restrict__ off0, const int* __restrict__ off1,
    const uint2* __restrict__ cw0, const uint2* __restrict__ cw1,
    const int* __restrict__ b0, const int* __restrict__ b1,
    const int* __restrict__ rng0, const int* __restrict__ rng1,
    const float* __restrict__ bias0, const float* __restrict__ bias1,
    float* __restrict__ pool0, float* __restrict__ pool1,
    float* __restrict__ scr0, float* __restrict__ scr1,
    int* __restrict__ gid0, int* __restrict__ gid1) {
  int br = blockIdx.y;
  const uint8_t* Hb = (const uint8_t*)(br ? H1 : H0);
  const int* off = br ? off1 : off0;
  const uint2* cw = br ? cw1 : cw0;
  const int* batch = br ? b1 : b0;
  const int* rng = br ? rng1 : rng0;
  const float* bias = br ? bias1 : bias0;
  float* pool = br ? pool1 : pool0;
  float* scratch = br ? scr1 : scr0;
  int* gid = br ? gid1 : gid0;

  int t = threadIdx.x;
  int wv = t >> 6, lane = t & 63, qw = lane >> 4, l16 = lane & 15;
  int slice = blockIdx.x & 7;
  int part = blockIdx.x >> 3;
  int q = part * 4 + wv;
  int d0 = slice * 128 + l16 * 8;
  unsigned d0b = (unsigned)d0 * 2;
  float4 bv0 = *(const float4*)(bias + d0);
  float4 bv1 = *(const float4*)(bias + d0 + 4);
  int na = rng[q], nb = rng[q + 1];
  int g0 = -1, g1 = -1;
  if (na < nb) {
    float bv[8] = {bv0.x, bv0.y, bv0.z, bv0.w, bv1.x, bv1.y, bv1.z, bv1.w};
    float pacc[8] = {};
    f32x2 a2[4] = {};
    int curg = batch[na];
    int fi = 0;
    int nd = na;
    int ee = off[na + 1];
    int eend = off[nb];
    int e = off[na];
    uint2 cc = cw[e + qw];
    uint2 cn = cw[e + 4 + qw];
    uint4 hc = *(const uint4*)(Hb + (cc.x + d0b));
#pragma unroll 2
    for (; e < eend; e += 4) {
      uint4 hn = *(const uint4*)(Hb + (cn.x + d0b));
      uint2 c2 = cw[e + 8 + qw];
      float w = __uint_as_float(cc.y);
      f32x2 w2; w2.x = w; w2.y = w;
      a2[0] += w2 * up2(hc.x);
      a2[1] += w2 * up2(hc.y);
      a2[2] += w2 * up2(hc.z);
      a2[3] += w2 * up2(hc.w);
      cc = cn; cn = c2; hc = hn;
      if (e + 4 == ee) {   // node nd complete (wave-uniform)
#pragma unroll
        for (int k = 0; k < 8; ++k) {
          float v = (k & 1) ? a2[k >> 1].y : a2[k >> 1].x;
          v += __shfl_xor(v, 16);
          v += __shfl_xor(v, 32);
          v += bv[k];
          pacc[k] += (v >= 0.f) ? v : 0.01f * v;
        }
#pragma unroll
        for (int k = 0; k < 4; ++k) { a2[k].x = 0.f; a2[k].y = 0.f; }
        ++nd;
        if (nd < nb) {
          ee = off[nd + 1];
          int g = batch[nd];
          if (g != curg) {
            if (fi == 0) {
              g0 = curg;
              if (qw == 0) {
                float* sp = scratch + ((long)q * 2 + 0) * 1024 + d0;
                *(float4*)sp = make_float4(pacc[0], pacc[1], pacc[2], pacc[3]);
                *(float4*)(sp + 4) = make_float4(pacc[4], pacc[5], pacc[6], pacc[7]);
              }
            } else {
              if (qw == 0) {
                float* pp = pool + (long)curg * 1024 + d0;
#pragma unroll
                for (int k = 0; k < 8; ++k) atomicAdd(pp + k, pacc[k]);
              }
            }
            ++fi;
#pragma unroll
            for (int k = 0; k < 8; ++k) pacc[k] = 0.f;
            curg = g;
          }
        }
      }
    }
    if (fi == 0) {
      g0 = curg;
      if (qw == 0) {
        float* sp = scratch + ((long)q * 2 + 0) * 1024 + d0;
        *(float4*)sp = make_float4(pacc[0], pacc[1], pacc[2], pacc[3]);
        *(float4*)(sp + 4) = make_float4(pacc[4], pacc[5], pacc[6], pacc[7]);
      }
    } else {
      g1 = curg;
      if (qw == 0) {
        float* sp = scratch + ((long)q * 2 + 1) * 1024 + d0;
        *(float4*)sp = make_float4(pacc[0], pacc[1], pacc[2], pacc[3]);
        *(float4*)(sp + 4) = make_float4(pacc[4], pacc[5], pacc[6], pacc[7]);
      }
    }
  }
  if (slice == 0 && lane == 0) {
    gid[q * 2] = g0;
    gid[q * 2 + 1] = g1;
  }
}

// ---------------- pool_reduce: scratch windows + pool + mean -> pm; init out ----------------
__global__ __launch_bounds__(256) void pool_reduce_kernel(
    const float* __restrict__ scr0, const float* __restrict__ scr1,
    const int* __restrict__ gid0, const int* __restrict__ gid1,
    const int* __restrict__ b0, const int* __restrict__ b1,
    const int* __restrict__ rng0, const int* __restrict__ rng1,
    const float* __restrict__ pool0, const float* __restrict__ pool1,
    float* __restrict__ pm0, float* __restrict__ pm1,
    const float* __restrict__ finb, float* __restrict__ out, int N, int nb_) {
  int br = blockIdx.y;
  const float* scratch = br ? scr1 : scr0;
  const int* gid = br ? gid1 : gid0;
  const int* batch = br ? b1 : b0;
  const int* rng = br ? rng1 : rng0;
  const float* pool = br ? pool1 : pool0;
  float* pm = br ? pm1 : pm0;
  int g = blockIdx.x >> 2;
  int slice = blockIdx.x & 3;
  int tid = threadIdx.x;
  if (br == 0 && blockIdx.x == 0 && tid < nb_) out[tid] = finb[0];
  int gs = lbound(batch, N, g), ge = lbound(batch, N, g + 1);
  float ic = 1.0f / (float)max(ge - gs, 1);
  int qlo = max(lbound(rng, NG + 1, gs + 1) - 1, 0);
  int qhi = min(lbound(rng, NG + 1, ge) - 1, NG - 1);
  long idx = (long)g * 1024 + slice * 256 + tid;
  float s = pool[idx];
  if (gs < ge) {
    for (int q = qlo; q <= qhi; ++q) {
      int a = gid[q * 2], b = gid[q * 2 + 1];
      if (a == g) s += scratch[((long)q * 2 + 0) * 1024 + slice * 256 + tid];
      if (b == g) s += scratch[((long)q * 2 + 1) * 1024 + slice * 256 + tid];
    }
  }
  pm[idx] = s * ic;
}

// ---------------- fc_head: per (graph, branch) FC + leaky + finW partial -> atomicAdd out ----
__global__ __launch_bounds__(512) void fc_head_kernel(
    const float* __restrict__ pm0, const float* __restrict__ pm1,
    const float* __restrict__ fc1W, const float* __restrict__ fc1b,
    const float* __restrict__ fc2W, const float* __restrict__ fc2b,
    const float* __restrict__ finW, float* __restrict__ out) {
  __shared__ float p[1024];
  __shared__ float red[512];
  int g = blockIdx.x, br = blockIdx.y, t = threadIdx.x;
  const float* pm = br ? pm1 : pm0;
  const float* W = br ? fc2W : fc1W;
  const float* bb = br ? fc2b : fc1b;
  for (int i = t; i < 1024; i += 512) p[i] = pm[(long)g * 1024 + i];
  __syncthreads();
  int col = t & 127, kq = t >> 7;
  const float* Wp = W + (long)(kq * 256) * 128 + col;
  const float* pk = p + kq * 256;
  float a = 0.f;
#pragma unroll 8
  for (int k = 0; k < 256; ++k) a += pk[k] * Wp[(long)k * 128];
  red[t] = a;
  __syncthreads();
  if (t < 128) {
    float s = red[t] + red[t + 128] + red[t + 256] + red[t + 384];
    s += bb[t];
    s = s >= 0.f ? s : 0.01f * s;
    red[t] = s * finW[br * 128 + t];
  }
  __syncthreads();
  for (int st = 64; st; st >>= 1) {
    if (t < st) red[t] += red[t + st];
    __syncthreads();
  }
  if (t == 0) atomicAdd(&out[g], red[0]);
}

extern "C" void kernel_launch(void* const* d_in, const int* in_sizes, int n_in,
                              void* d_out, int out_size, void* d_ws, size_t ws_size,
                              hipStream_t stream) {
  (void)n_in; (void)ws_size;
  const float* xs[2]   = {(const float*)d_in[0], (const float*)d_in[3]};
  const int* eis[2]    = {(const int*)d_in[1], (const int*)d_in[4]};
  const int* bts[2]    = {(const int*)d_in[2], (const int*)d_in[5]};
  const float* Ws[2]   = {(const float*)d_in[6], (const float*)d_in[10]};
  const float* bs[2]   = {(const float*)d_in[7], (const float*)d_in[11]};
  const float* fc1W = (const float*)d_in[8];
  const float* fc1b = (const float*)d_in[9];
  const float* fc2W = (const float*)d_in[12];
  const float* fc2b = (const float*)d_in[13];
  const float* finW = (const float*)d_in[14];
  const float* finb = (const float*)d_in[15];
  float* out = (float*)d_out;

  const int N = in_sizes[2];
  const int E = in_sizes[1] / 2;
  const int Mpad = ((N + 1023) / 1024) * 1024;   // MT multiple of 8 for XCD mapping
  const int MT = Mpad / BM;
  const int CWCAP = E + 4 * N + 64;

  uint8_t* ws = (uint8_t*)d_ws;
  size_t o = 0;
  auto alloc = [&](size_t bytes) { size_t r = o; o += (bytes + 255) & ~(size_t)255; return r; };
  size_t degi_o[2] = {alloc((size_t)N * 4), alloc((size_t)N * 4)};
  size_t pool_o[2] = {alloc((size_t)out_size * 1024 * 4), alloc((size_t)out_size * 1024 * 4)};
  size_t cw_o[2]   = {alloc((size_t)CWCAP * 8), alloc((size_t)CWCAP * 8)};
  size_t zero_end = o;
  size_t cur_o[2]  = {alloc((size_t)N * 4), alloc((size_t)N * 4)};
  size_t off_o[2]  = {alloc((size_t)(N + 1) * 4), alloc((size_t)(N + 1) * 4)};
  size_t rng_o[2]  = {alloc((size_t)(NG + 1) * 4), alloc((size_t)(NG + 1) * 4)};
  size_t gid_o[2]  = {alloc((size_t)NG * 2 * 4), alloc((size_t)NG * 2 * 4)};
  size_t scr_o[2]  = {alloc((size_t)NG * 2 * 1024 * 4), alloc((size_t)NG * 2 * 1024 * 4)};
  size_t pm_o[2]   = {alloc((size_t)out_size * 1024 * 4), alloc((size_t)out_size * 1024 * 4)};
  size_t xb_o[2]   = {alloc((size_t)Mpad * 1024 * 2), alloc((size_t)Mpad * 1024 * 2)};
  size_t wt_o[2]   = {alloc((size_t)1024 * 1024 * 2), alloc((size_t)1024 * 1024 * 2)};
  size_t h_o[2]    = {alloc((size_t)Mpad * 1024 * 2), alloc((size_t)Mpad * 1024 * 2)};

  (void)hipMemsetAsync(ws, 0, zero_end, stream);

  const int CB = (int)(((long)Mpad * 128 + 255) / 256);
  const int DB = (E + 255) / 256;
  prep1_kernel<<<dim3(CB + 1024 + DB, 2), 256, 0, stream>>>(
      xs[0], xs[1], (unsigned short*)(ws + xb_o[0]), (unsigned short*)(ws + xb_o[1]),
      Ws[0], Ws[1], (unsigned short*)(ws + wt_o[0]), (unsigned short*)(ws + wt_o[1]),
      eis[0], eis[1], (int*)(ws + degi_o[0]), (int*)(ws + degi_o[1]),
      N, Mpad, E, CB);
  scan2_kernel<<<2, 1024, 0, stream>>>(
      (const int*)(ws + degi_o[0]), (int*)(ws + off_o[0]), (int*)(ws + cur_o[0]),
      (const int*)(ws + degi_o[1]), (int*)(ws + off_o[1]), (int*)(ws + cur_o[1]), N);
  const int FB = (E + N + 255) / 256;
  const int RB = (NG + 256) / 256;
  prep2_kernel<<<dim3(FB + RB, 2), 256, 0, stream>>>(
      eis[0], eis[1], (const int*)(ws + degi_o[0]), (const int*)(ws + degi_o[1]),
      (int*)(ws + cur_o[0]), (int*)(ws + cur_o[1]),
      (uint2*)(ws + cw_o[0]), (uint2*)(ws + cw_o[1]),
      (const int*)(ws + off_o[0]), (const int*)(ws + off_o[1]),
      (int*)(ws + rng_o[0]), (int*)(ws + rng_o[1]), E, N, FB);
  gemm_bf16_kernel<<<dim3(MT * 8, 1, 2), 256, 0, stream>>>(
      (const unsigned short*)(ws + xb_o[0]), (const unsigned short*)(ws + xb_o[1]),
      (const unsigned short*)(ws + wt_o[0]), (const unsigned short*)(ws + wt_o[1]),
      (unsigned short*)(ws + h_o[0]), (unsigned short*)(ws + h_o[1]), 1024, 1024);
  agg_pool_kernel<<<dim3((NG / 4) * NSL, 2), 256, 0, stream>>>(
      (const unsigned short*)(ws + h_o[0]), (const unsigned short*)(ws + h_o[1]),
      (const int*)(ws + off_o[0]), (const int*)(ws + off_o[1]),
      (const uint2*)(ws + cw_o[0]), (const uint2*)(ws + cw_o[1]),
      bts[0], bts[1],
      (const int*)(ws + rng_o[0]), (const int*)(ws + rng_o[1]),
      bs[0], bs[1],
      (float*)(ws + pool_o[0]), (float*)(ws + pool_o[1]),
      (float*)(ws + scr_o[0]), (float*)(ws + scr_o[1]),
      (int*)(ws + gid_o[0]), (int*)(ws + gid_o[1]));
  pool_reduce_kernel<<<dim3(out_size * 4, 2), 256, 0, stream>>>(
      (const float*)(ws + scr_o[0]), (const float*)(ws + scr_o[1]),
      (const int*)(ws + gid_o[0]), (const int*)(ws + gid_o[1]),
      bts[0], bts[1],
      (const int*)(ws + rng_o[0]), (const int*)(ws + rng_o[1]),
      (const float*)(ws + pool_o[0]), (const float*)(ws + pool_o[1]),
      (float*)(ws + pm_o[0]), (float*)(ws + pm_o[1]),
      finb, out, N, out_size);
  fc_head_kernel<<<dim3(out_size, 2), 512, 0, stream>>>(
      (const float*)(ws + pm_o[0]), (const float*)(ws + pm_o[1]),
      fc1W, fc1b, fc2W, fc2b, finW, out);
}